// Round 5
// baseline (181.646 us; speedup 1.0000x reference)
//
#include <hip/hip_runtime.h>
#include <hip/hip_bf16.h>

// CALIBRATION ROUND: identical math, but the full output is produced TWICE
// (pass 0 -> d_ws scratch, pass 1 -> d_out). Purpose: (1) make the kernel
// exceed the ~86us poison-fill dispatches so it appears in the rocprof top-5
// with its own counters; (2) dur_us delta vs R4 discriminates whether dur_us
// includes harness fills (dur ~= OH + 2T) or is kernel-only (dur ~= 2*dur_R4).

#define BB     16
#define QQ     2048
#define NCLS   2
#define DBOX   6
#define TT     1024
#define ROWS   (BB * QQ)          // 32768 (b,q) rows
#define TPB    256                // threads per block
#define TPT    4                  // targets per thread: 256*4 = 1024 = TT
#define RPB    32                 // rows per block: grid = 1024 blocks
#define RCHUNK 4                  // rows processed together (ILP / MLP)

typedef float v4f __attribute__((ext_vector_type(4)));

__global__ __launch_bounds__(TPB) void hungarian_cost_kernel(
    const float* __restrict__ logits,   // (ROWS, NCLS) f32
    const float* __restrict__ boxes,    // (ROWS, DBOX) f32
    const int*   __restrict__ labels,   // (TT,) int32
    const float* __restrict__ tboxes,   // (TT, DBOX) f32
    float*       __restrict__ scratch,  // (ROWS, TT) f32 — calibration sink
    float*       __restrict__ out)      // (ROWS, TT) f32
{
    const int tid = threadIdx.x;
    const int t0  = tid * TPT;

    // --- Preload this thread's 4 targets into registers (once per block) ---
    float tb[TPT][DBOX];
    float w[TPT];
#pragma unroll
    for (int j = 0; j < TPT; ++j) {
        const int t = t0 + j;
#pragma unroll
        for (int d = 0; d < DBOX; ++d) tb[j][d] = tboxes[t * DBOX + d];
        w[j] = (float)labels[t];
    }

    const int row0 = blockIdx.x * RPB;

#pragma unroll 1
    for (int pass = 0; pass < 2; ++pass) {
        float* __restrict__ dst = (pass == 0) ? scratch : out;

#pragma unroll 1
        for (int rc = 0; rc < RPB; rc += RCHUNK) {
            float l0v[RCHUNK], l1v[RCHUNK], qb[RCHUNK][DBOX];
#pragma unroll
            for (int r = 0; r < RCHUNK; ++r) {
                const int row = row0 + rc + r;     // wave-uniform
                l0v[r] = logits[row * NCLS + 0];
                l1v[r] = logits[row * NCLS + 1];
#pragma unroll
                for (int d = 0; d < DBOX; ++d) qb[r][d] = boxes[row * DBOX + d];
            }

            float p0v[RCHUNK], d10v[RCHUNK];
#pragma unroll
            for (int r = 0; r < RCHUNK; ++r) {
                const float e0  = __expf(l0v[r]);
                const float e1  = __expf(l1v[r]);
                const float inv = 1.0f / (e0 + e1);
                p0v[r]  = e0 * inv;
                d10v[r] = (e1 - e0) * inv;         // p1 - p0
            }

#pragma unroll
            for (int r = 0; r < RCHUNK; ++r) {
                const int row = row0 + rc + r;
                float c[TPT];
#pragma unroll
                for (int j = 0; j < TPT; ++j) {
                    float s = 0.0f;
#pragma unroll
                    for (int d = 0; d < DBOX; ++d) s += fabsf(qb[r][d] - tb[j][d]);
                    c[j] = 5.0f * s - (p0v[r] + w[j] * d10v[r]);
                }
                v4f v = { c[0], c[1], c[2], c[3] };
                __builtin_nontemporal_store(v,
                    reinterpret_cast<v4f*>(dst + (size_t)row * TT + t0));
            }
        }
    }
}

extern "C" void kernel_launch(void* const* d_in, const int* in_sizes, int n_in,
                              void* d_out, int out_size, void* d_ws, size_t ws_size,
                              hipStream_t stream) {
    const float* logits = (const float*)d_in[0];   // (B,Q,NCLS) f32
    const float* boxes  = (const float*)d_in[1];   // (B,Q,DBOX) f32
    const int*   labels = (const int*)  d_in[2];   // (T,) int
    const float* tboxes = (const float*)d_in[3];   // (T,DBOX) f32
    float*       out    = (float*)d_out;           // (B,Q,T) f32

    const size_t need = (size_t)ROWS * TT * sizeof(float);   // 128 MiB
    float* scratch = (ws_size >= need) ? (float*)d_ws : out; // fallback: double-write d_out

    const int grid = ROWS / RPB;  // 1024
    hungarian_cost_kernel<<<grid, TPB, 0, stream>>>(logits, boxes, labels, tboxes, scratch, out);
}

// Round 6
// 148.154 us; speedup vs baseline: 1.2261x; 1.2261x over previous
//
#include <hip/hip_runtime.h>
#include <hip/hip_bf16.h>

// Final kernel: revert to the best-measured structure (Round 2, 146.5 us).
// Calibration (R5 double-pass probe): one full output pass costs ~25.7 us
// (128 MiB @ ~5.2 TB/s, ~83% of the fill's achieved 6.25 TB/s write BW);
// dur_us carries ~130 us of fixed harness re-poison overhead. Remaining
// controllable headroom is <= ~4 us (~3% of metric), within session noise.

#define BB     16
#define QQ     2048
#define NCLS   2
#define DBOX   6
#define TT     1024
#define ROWS   (BB * QQ)          // 32768 (b,q) rows
#define TPB    256                // threads per block
#define TPT    4                  // targets per thread: 256*4 = 1024 = TT
#define RPB    16                 // rows per block: grid = 32768/16 = 2048 blocks

__global__ __launch_bounds__(TPB) void hungarian_cost_kernel(
    const float* __restrict__ logits,   // (ROWS, NCLS) f32
    const float* __restrict__ boxes,    // (ROWS, DBOX) f32
    const int*   __restrict__ labels,   // (TT,) int32
    const float* __restrict__ tboxes,   // (TT, DBOX) f32
    float*       __restrict__ out)      // (ROWS, TT) f32
{
    const int tid = threadIdx.x;
    const int t0  = tid * TPT;

    // --- Preload this thread's 4 targets into registers (once per block) ---
    float tb[TPT][DBOX];
    float w[TPT];
#pragma unroll
    for (int j = 0; j < TPT; ++j) {
        const int t = t0 + j;
#pragma unroll
        for (int d = 0; d < DBOX; ++d) tb[j][d] = tboxes[t * DBOX + d];
        w[j] = (float)labels[t];    // label in {0,1} -> selector weight
    }

    const int row0 = blockIdx.x * RPB;

#pragma unroll 1
    for (int r = 0; r < RPB; ++r) {
        const int row = row0 + r;   // wave-uniform -> scalar loads

        // 2-class softmax: p[label] = p0 + label*(p1-p0)
        const float l0  = logits[row * NCLS + 0];
        const float l1  = logits[row * NCLS + 1];
        const float e0  = __expf(l0);
        const float e1  = __expf(l1);
        const float inv = 1.0f / (e0 + e1);
        const float p0  = e0 * inv;
        const float d10 = (e1 - e0) * inv;   // p1 - p0

        float qb[DBOX];
#pragma unroll
        for (int d = 0; d < DBOX; ++d) qb[d] = boxes[row * DBOX + d];

        float c[TPT];
#pragma unroll
        for (int j = 0; j < TPT; ++j) {
            float s = 0.0f;
#pragma unroll
            for (int d = 0; d < DBOX; ++d) s += fabsf(qb[d] - tb[j][d]);
            c[j] = 5.0f * s - (p0 + w[j] * d10);
        }

        float4 v = make_float4(c[0], c[1], c[2], c[3]);
        *reinterpret_cast<float4*>(out + (size_t)row * TT + t0) = v;  // 16B aligned
    }
}

extern "C" void kernel_launch(void* const* d_in, const int* in_sizes, int n_in,
                              void* d_out, int out_size, void* d_ws, size_t ws_size,
                              hipStream_t stream) {
    const float* logits = (const float*)d_in[0];   // (B,Q,NCLS) f32
    const float* boxes  = (const float*)d_in[1];   // (B,Q,DBOX) f32
    const int*   labels = (const int*)  d_in[2];   // (T,) int
    const float* tboxes = (const float*)d_in[3];   // (T,DBOX) f32
    float*       out    = (float*)d_out;           // (B,Q,T) f32

    const int grid = ROWS / RPB;  // 2048
    hungarian_cost_kernel<<<grid, TPB, 0, stream>>>(logits, boxes, labels, tboxes, out);
}